// Round 1
// baseline (474.159 us; speedup 1.0000x reference)
//
#include <hip/hip_runtime.h>
#include <cstdint>
#include <cstddef>

#define Tn 1024
#define Bn 64
#define Cn 8
#define Nn 64
#define TBC_STRIDE (Bn*Cn)        /* 512: tags stride per t   */
#define EM_T_STRIDE (Bn*Cn*Nn)    /* 32768: emissions stride per t */

// ---- wave64 reductions via DPP (row_shr 1/2/4/8, row_bcast15/31) ----
__device__ __forceinline__ float wred_max(float x) {
  int v;
#define STEP(ctrl) \
  v = __builtin_amdgcn_update_dpp((int)0xff800000, __float_as_int(x), ctrl, 0xf, 0xf, false); \
  x = fmaxf(x, __int_as_float(v));
  STEP(0x111) STEP(0x112) STEP(0x114) STEP(0x118) STEP(0x142) STEP(0x143)
#undef STEP
  return __int_as_float(__builtin_amdgcn_readlane(__float_as_int(x), 63));
}

__device__ __forceinline__ float wred_sum(float x) {
  int v;
#define STEP(ctrl) \
  v = __builtin_amdgcn_update_dpp(0, __float_as_int(x), ctrl, 0xf, 0xf, false); \
  x = x + __int_as_float(v);
  STEP(0x111) STEP(0x112) STEP(0x114) STEP(0x118) STEP(0x142) STEP(0x143)
#undef STEP
  return __int_as_float(__builtin_amdgcn_readlane(__float_as_int(x), 63));
}

__global__ __launch_bounds__(256, 2)
void crf_fwd(const float* __restrict__ em, const int* __restrict__ tags,
             const int* __restrict__ lengths, const float* __restrict__ trans,
             const float* __restrict__ head, const float* __restrict__ tail,
             float* __restrict__ out) {
  __shared__ float trans_lds[Nn * Nn];     // raw transitions[c] (16 KB)
  __shared__ float part[2][4][Nn];         // double-buffered per-wave partials
  __shared__ float scores[5];              // 4 wave score sums + head/tail

  const int bid = blockIdx.x;              // 512 blocks = B*C chains
  const int b = bid >> 3, c = bid & 7;
  const int tid = threadIdx.x;
  const int w = __builtin_amdgcn_readfirstlane(tid >> 6);  // wave id 0..3 (SGPR)
  const int lane = tid & 63;
  const int j = lane;                      // output column this lane owns
  const int len = lengths[b];              // in [512, 1024]

  // ---- stage transitions[c] into LDS (coalesced) ----
  const float* tc = trans + c * Nn * Nn;
  for (int k = tid; k < Nn * Nn; k += 256) trans_lds[k] = tc[k];
  __syncthreads();

  // ---- per-lane column max + exp'd P column fragment (16 rows per wave) ----
  float colmax = -__builtin_inff();
  for (int i = 0; i < Nn; ++i) colmax = fmaxf(colmax, trans_lds[i * Nn + j]);
  float Pcol[16];
#pragma unroll
  for (int k = 0; k < 16; ++k)
    Pcol[k] = __expf(trans_lds[(w * 16 + k) * Nn + j] - colmax);

  // ---- log_scores phase: T split across 256 threads ----
  float sc = 0.f;
#pragma unroll
  for (int it = 0; it < 4; ++it) {
    int t = tid + it * 256;
    if (t < len) {
      int tagc = tags[t * TBC_STRIDE + b * Cn + c];
      sc += em[(size_t)t * EM_T_STRIDE + (size_t)(b * Cn + c) * Nn + tagc];
      if (t >= 1) {
        int tagp = tags[(t - 1) * TBC_STRIDE + b * Cn + c];
        sc += trans_lds[tagp * Nn + tagc];
      }
    }
  }
  sc = wred_sum(sc);
  if (lane == 63) scores[w] = sc;
  if (tid == 0) {
    int tag0 = tags[b * Cn + c];
    int tagl = tags[(len - 1) * TBC_STRIDE + b * Cn + c];
    scores[4] = head[c * Nn + tag0] + tail[c * Nn + tagl];
  }

  // ---- forward recursion (replicated alpha across the 4 waves) ----
  const float* emB = em + (size_t)(b * Cn + c) * Nn + j;  // &em[0,b,c,j]
  float alpha = head[c * Nn + j] + emB[0];
  float em_cur = emB[(size_t)1 * EM_T_STRIDE];            // t = 1 (len >= 512)
  __syncthreads();  // scores[] written; part[] about to be used

  int buf = 0;
  for (int t = 1; t < len; ++t) {
    int tn = (t + 1 < Tn) ? (t + 1) : t;
    float em_next = emB[(size_t)tn * EM_T_STRIDE];        // prefetch next step

    float maxA = wred_max(alpha);
    float E = __expf(alpha - maxA);
    int Ei = __float_as_int(E);

    float a0 = 0.f, a1 = 0.f, a2 = 0.f, a3 = 0.f;
#pragma unroll
    for (int k = 0; k < 4; ++k) {
      a0 += __int_as_float(__builtin_amdgcn_readlane(Ei, w * 16 + 4 * k + 0)) * Pcol[4 * k + 0];
      a1 += __int_as_float(__builtin_amdgcn_readlane(Ei, w * 16 + 4 * k + 1)) * Pcol[4 * k + 1];
      a2 += __int_as_float(__builtin_amdgcn_readlane(Ei, w * 16 + 4 * k + 2)) * Pcol[4 * k + 2];
      a3 += __int_as_float(__builtin_amdgcn_readlane(Ei, w * 16 + 4 * k + 3)) * Pcol[4 * k + 3];
    }
    part[buf][w][j] = (a0 + a1) + (a2 + a3);
    __syncthreads();
    float s = (part[buf][0][j] + part[buf][1][j]) + (part[buf][2][j] + part[buf][3][j]);
    alpha = maxA + colmax + __logf(s) + em_cur;
    em_cur = em_next;
    buf ^= 1;
  }

  // ---- final: log_partition + output ----
  if (w == 0) {
    float vfin = alpha + tail[c * Nn + j];
    float m = wred_max(vfin);
    float e = __expf(vfin - m);
    float ssum = wred_sum(e);
    if (lane == 63) {
      float lp = m + __logf(ssum);
      float total = ((scores[0] + scores[1]) + (scores[2] + scores[3])) + scores[4];
      out[b * Cn + c] = total - lp;
    }
  }
}

extern "C" void kernel_launch(void* const* d_in, const int* in_sizes, int n_in,
                              void* d_out, int out_size, void* d_ws, size_t ws_size,
                              hipStream_t stream) {
  const float* em      = (const float*)d_in[0];
  const int*   tags    = (const int*)d_in[1];
  const int*   lengths = (const int*)d_in[2];
  const float* trans   = (const float*)d_in[3];
  const float* head    = (const float*)d_in[4];
  const float* tail    = (const float*)d_in[5];
  float* out = (float*)d_out;
  crf_fwd<<<dim3(Bn * Cn), dim3(256), 0, stream>>>(em, tags, lengths, trans, head, tail, out);
}

// Round 3
// 340.949 us; speedup vs baseline: 1.3907x; 1.3907x over previous
//
#include <hip/hip_runtime.h>
#include <cstdint>
#include <cstddef>

#define Tn 1024
#define Bn 64
#define Cn 8
#define Nn 64
#define TBC 512            /* tags stride per t */
#define ES 32768           /* emissions stride per t (B*C*N) */

// ---- wave64 reductions via DPP (row_shr 1/2/4/8, row_bcast15/31) ----
__device__ __forceinline__ float wred_max(float x) {
  int v;
#define STEP(ctrl) \
  v = __builtin_amdgcn_update_dpp((int)0xff800000, __float_as_int(x), ctrl, 0xf, 0xf, false); \
  x = fmaxf(x, __int_as_float(v));
  STEP(0x111) STEP(0x112) STEP(0x114) STEP(0x118) STEP(0x142) STEP(0x143)
#undef STEP
  return __int_as_float(__builtin_amdgcn_readlane(__float_as_int(x), 63));
}

__device__ __forceinline__ float wred_sum(float x) {
  int v;
#define STEP(ctrl) \
  v = __builtin_amdgcn_update_dpp(0, __float_as_int(x), ctrl, 0xf, 0xf, false); \
  x = x + __int_as_float(v);
  STEP(0x111) STEP(0x112) STEP(0x114) STEP(0x118) STEP(0x142) STEP(0x143)
#undef STEP
  return __int_as_float(__builtin_amdgcn_readlane(__float_as_int(x), 63));
}

__device__ __forceinline__ float lane0(float x) {
  return __int_as_float(__builtin_amdgcn_readlane(__float_as_int(x), 0));
}

// In-wave 64x64 matvec: s[lane] = sum_k E_bcast[k] * P[k]
// E is broadcast through LDS (ds_write_b32 + 16 broadcast ds_read_b128).
// In-wave LDS ops complete in program order; the asm fences stop hipcc from
// reordering the read cluster across the write (rule #18 class of hazard).
__device__ __forceinline__ float matvec(float* ew, const float (&P)[64], float E, int lane) {
  __asm__ __volatile__("" ::: "memory");
  ew[lane] = E;
  __builtin_amdgcn_wave_barrier();
  __asm__ __volatile__("" ::: "memory");
  const float4* e4 = (const float4*)ew;
  float acc[8];
#pragma unroll
  for (int q = 0; q < 8; ++q) {
    float4 u = e4[q];
    acc[q] = fmaf(u.x, P[4*q+0], fmaf(u.y, P[4*q+1], fmaf(u.z, P[4*q+2], u.w * P[4*q+3])));
  }
#pragma unroll
  for (int q = 0; q < 8; ++q) {
    float4 u = e4[q+8];
    acc[q] = fmaf(u.x, P[32+4*q+0], fmaf(u.y, P[32+4*q+1], fmaf(u.z, P[32+4*q+2], fmaf(u.w, P[32+4*q+3], acc[q]))));
  }
  __builtin_amdgcn_wave_barrier();
  __asm__ __volatile__("" ::: "memory");
  return ((acc[0]+acc[1]) + (acc[2]+acc[3])) + ((acc[4]+acc[5]) + (acc[6]+acc[7]));
}

// One forward step: alpha'_j = M + log(sum_i e^{alpha_i - M} e^{trans_ij}) + em_t[j]
#define FSTEP(alpha, emv) do {                 \
    float M_ = lane0(alpha);                   \
    float E_ = __expf((alpha) - M_);           \
    float s_ = matvec(ew, P, E_, lane);        \
    (alpha) = M_ + __logf(s_) + (emv);         \
  } while (0)

// One backward step: b_i = M + log(sum_j e^{trans_ij} e^{(b_j + em_{t+1,j}) - M})
#define BSTEP(bv, emv) do {                    \
    float v_ = (bv) + (emv);                   \
    float M_ = lane0(v_);                      \
    float F_ = __expf(v_ - M_);                \
    float s_ = matvec(ew, P, F_, lane);        \
    (bv) = M_ + __logf(s_);                    \
  } while (0)

__global__ __launch_bounds__(128)
void crf_fwd(const float* __restrict__ em, const int* __restrict__ tags,
             const int* __restrict__ lengths, const float* __restrict__ trans,
             const float* __restrict__ head, const float* __restrict__ tail,
             float* __restrict__ out) {
  __shared__ float trans_lds[Nn * Nn];              // 16 KB, transitions[c]
  __shared__ __align__(16) float ebuf[2][Nn];       // per-wave E broadcast buffer
  __shared__ float blds[Nn];                        // beta at meeting point
  __shared__ float scw[2];                          // per-wave score partials
  __shared__ float sc_ht;                           // head+tail score

  const int bid = blockIdx.x;                       // 512 = B*C chains
  const int b = bid >> 3, c = bid & 7;
  const int tid = threadIdx.x;
  const int w = __builtin_amdgcn_readfirstlane(tid >> 6);  // 0 = fwd wave, 1 = bwd wave
  const int lane = tid & 63;
  const int bc = b * Cn + c;
  const int len = lengths[b];                       // in [512, 1024]
  const int m = len >> 1;                           // meeting point

  // ---- stage transitions[c] into LDS (coalesced) ----
  const float* tc = trans + c * Nn * Nn;
  for (int k = tid; k < Nn * Nn; k += 128) trans_lds[k] = tc[k];
  __syncthreads();

  // ---- log_scores phase: T split across 128 threads ----
  float sc = 0.f;
#pragma unroll
  for (int it = 0; it < 8; ++it) {
    int t = it * 128 + tid;
    if (t < len) {
      int tagc = tags[t * TBC + bc];
      sc += em[(size_t)t * ES + (size_t)bc * Nn + tagc];
      if (t >= 1) {
        int tagp = tags[(t - 1) * TBC + bc];
        sc += trans_lds[tagp * Nn + tagc];
      }
    }
  }
  sc = wred_sum(sc);
  if (lane == 0) scw[w] = sc;
  if (tid == 0) {
    int tag0 = tags[bc];
    int tagl = tags[(len - 1) * TBC + bc];
    sc_ht = head[c * Nn + tag0] + tail[c * Nn + tagl];
  }

  // ---- per-wave P fragment: fwd wave holds column `lane`, bwd wave row `lane` ----
  float P[64];
  if (w == 0) {
#pragma unroll
    for (int k = 0; k < 64; ++k) P[k] = __expf(trans_lds[k * Nn + lane]);
  } else {
#pragma unroll
    for (int k = 0; k < 64; ++k) P[k] = __expf(trans_lds[lane * Nn + k]);
  }

  const float* emB = em + (size_t)bc * Nn + lane;   // &em[0, b, c, lane]
  float* ew = ebuf[w];
  float state = 0.f;

  if (w == 0) {
    // ======== forward: steps t = 1..m ========
    float alpha = head[c * Nn + lane] + emB[0];
    float e0 = emB[(size_t)1 * ES], e1 = emB[(size_t)2 * ES],
          e2 = emB[(size_t)3 * ES], e3 = emB[(size_t)4 * ES];
    int t = 1;
    for (; t + 3 <= m; t += 4) {                    // prefetch t+4..t+7 (<= m+4 <= 516, in-bounds)
      FSTEP(alpha, e0); e0 = emB[(size_t)(t + 4) * ES];
      FSTEP(alpha, e1); e1 = emB[(size_t)(t + 5) * ES];
      FSTEP(alpha, e2); e2 = emB[(size_t)(t + 6) * ES];
      FSTEP(alpha, e3); e3 = emB[(size_t)(t + 7) * ES];
    }
    if (t <= m) { FSTEP(alpha, e0); ++t; }
    if (t <= m) { FSTEP(alpha, e1); ++t; }
    if (t <= m) { FSTEP(alpha, e2); ++t; }
    state = alpha;                                  // alpha_m
  } else {
    // ======== backward: b_{len-1}=tail; steps t = len-2 down to m (uses em[t+1]) ========
    float bv = tail[c * Nn + lane];
    const int nb = len - 1 - m;                     // step count; k-th step uses em[len-1-k]
    float e0 = emB[(size_t)(len - 1) * ES], e1 = emB[(size_t)(len - 2) * ES],
          e2 = emB[(size_t)(len - 3) * ES], e3 = emB[(size_t)(len - 4) * ES];
    int k = 0;
    for (; k + 4 <= nb; k += 4) {                   // prefetch len-5-k .. len-8-k (>= m-3 >= 0)
      BSTEP(bv, e0); e0 = emB[(size_t)(len - 5 - k) * ES];
      BSTEP(bv, e1); e1 = emB[(size_t)(len - 6 - k) * ES];
      BSTEP(bv, e2); e2 = emB[(size_t)(len - 7 - k) * ES];
      BSTEP(bv, e3); e3 = emB[(size_t)(len - 8 - k) * ES];
    }
    if (k < nb) { BSTEP(bv, e0); ++k; }
    if (k < nb) { BSTEP(bv, e1); ++k; }
    if (k < nb) { BSTEP(bv, e2); ++k; }
    blds[lane] = bv;                                // beta_m
  }

  __syncthreads();                                  // single barrier: both waves hit once

  if (w == 0) {
    float v = state + blds[lane];                   // alpha_m + beta_m
    float mm = wred_max(v);
    float ssum = wred_sum(__expf(v - mm));
    if (lane == 0) {
      float logZ = mm + __logf(ssum);
      out[bc] = scw[0] + scw[1] + sc_ht - logZ;
    }
  }
}

extern "C" void kernel_launch(void* const* d_in, const int* in_sizes, int n_in,
                              void* d_out, int out_size, void* d_ws, size_t ws_size,
                              hipStream_t stream) {
  const float* em      = (const float*)d_in[0];
  const int*   tags    = (const int*)d_in[1];
  const int*   lengths = (const int*)d_in[2];
  const float* trans   = (const float*)d_in[3];
  const float* head    = (const float*)d_in[4];
  const float* tail    = (const float*)d_in[5];
  float* out = (float*)d_out;
  crf_fwd<<<dim3(Bn * Cn), dim3(128), 0, stream>>>(em, tags, lengths, trans, head, tail, out);
}

// Round 4
// 245.370 us; speedup vs baseline: 1.9324x; 1.3895x over previous
//
#include <hip/hip_runtime.h>
#include <cstdint>
#include <cstddef>

#define Tn 1024
#define Bn 64
#define Cn 8
#define Nn 64
#define LDP 65             /* padded row stride for trans_lds (bank-conflict-free rows AND cols) */
#define TBC 512            /* tags stride per t */
#define ES 32768           /* emissions stride per t (B*C*N) */

// ---- wave64 reductions via DPP (row_shr 1/2/4/8, row_bcast15/31) ----
__device__ __forceinline__ float wred_max(float x) {
  int v;
#define STEP(ctrl) \
  v = __builtin_amdgcn_update_dpp((int)0xff800000, __float_as_int(x), ctrl, 0xf, 0xf, false); \
  x = fmaxf(x, __int_as_float(v));
  STEP(0x111) STEP(0x112) STEP(0x114) STEP(0x118) STEP(0x142) STEP(0x143)
#undef STEP
  return __int_as_float(__builtin_amdgcn_readlane(__float_as_int(x), 63));
}

__device__ __forceinline__ float wred_sum(float x) {
  int v;
#define STEP(ctrl) \
  v = __builtin_amdgcn_update_dpp(0, __float_as_int(x), ctrl, 0xf, 0xf, false); \
  x = x + __int_as_float(v);
  STEP(0x111) STEP(0x112) STEP(0x114) STEP(0x118) STEP(0x142) STEP(0x143)
#undef STEP
  return __int_as_float(__builtin_amdgcn_readlane(__float_as_int(x), 63));
}

__device__ __forceinline__ float lane0(float x) {
  return __int_as_float(__builtin_amdgcn_readlane(__float_as_int(x), 0));
}

// ---- in-register 64x64 matvec via readlane broadcast ----
// P is referenced BY NAME (never address-taken) so it stays in VGPRs.
#define RL(k) __int_as_float(__builtin_amdgcn_readlane(Ei_, (k)))
#define MV8(base) \
  a0_ = fmaf(RL(base + 0), P[base + 0], a0_); \
  a1_ = fmaf(RL(base + 1), P[base + 1], a1_); \
  a2_ = fmaf(RL(base + 2), P[base + 2], a2_); \
  a3_ = fmaf(RL(base + 3), P[base + 3], a3_); \
  a4_ = fmaf(RL(base + 4), P[base + 4], a4_); \
  a5_ = fmaf(RL(base + 5), P[base + 5], a5_); \
  a6_ = fmaf(RL(base + 6), P[base + 6], a6_); \
  a7_ = fmaf(RL(base + 7), P[base + 7], a7_);
#define MV64_BODY() \
  float a0_ = 0.f, a1_ = 0.f, a2_ = 0.f, a3_ = 0.f, a4_ = 0.f, a5_ = 0.f, a6_ = 0.f, a7_ = 0.f; \
  MV8(0) MV8(8) MV8(16) MV8(24) MV8(32) MV8(40) MV8(48) MV8(56) \
  float s_ = ((a0_ + a1_) + (a2_ + a3_)) + ((a4_ + a5_) + (a6_ + a7_));

// Forward step: alpha'_j = M + log(sum_i e^{alpha_i - M} * P[i][j]) + em_t[j]
#define FSTEP(alpha, emv) do {                      \
    float M_ = lane0(alpha);                        \
    int Ei_ = __float_as_int(__expf((alpha) - M_)); \
    MV64_BODY();                                    \
    (alpha) = M_ + __logf(s_) + (emv);              \
  } while (0)

// Backward step: b_i = M + log(sum_j P[i][j] * e^{(b_j + em_{t+1,j}) - M})
#define BSTEP(bv, emv) do {                         \
    float v_ = (bv) + (emv);                        \
    float M_ = lane0(v_);                           \
    int Ei_ = __float_as_int(__expf(v_ - M_));      \
    MV64_BODY();                                    \
    (bv) = M_ + __logf(s_);                         \
  } while (0)

__global__ __launch_bounds__(128)
void crf_fwd(const float* __restrict__ em, const int* __restrict__ tags,
             const int* __restrict__ lengths, const float* __restrict__ trans,
             const float* __restrict__ head, const float* __restrict__ tail,
             float* __restrict__ out) {
  __shared__ float trans_lds[Nn * LDP];             // padded transitions[c], 16.6 KB
  __shared__ float blds[Nn];                        // beta at meeting point
  __shared__ float scw[2];                          // per-wave score partials
  __shared__ float sc_ht;                           // head+tail score

  const int bid = blockIdx.x;                       // 512 = B*C chains
  const int b = bid >> 3, c = bid & 7;
  const int tid = threadIdx.x;
  const int w = __builtin_amdgcn_readfirstlane(tid >> 6);  // 0 = fwd wave, 1 = bwd wave
  const int lane = tid & 63;
  const int bc = b * Cn + c;
  const int len = lengths[b];                       // in [512, 1024]
  const int m = len >> 1;                           // meeting point

  // ---- stage transitions[c] into LDS, padded stride 65 ----
  const float* tc = trans + c * Nn * Nn;
  for (int k = tid; k < Nn * Nn; k += 128) trans_lds[(k >> 6) * LDP + (k & 63)] = tc[k];
  __syncthreads();

  // ---- log_scores phase: T split across 128 threads ----
  float sc = 0.f;
#pragma unroll
  for (int it = 0; it < 8; ++it) {
    int t = it * 128 + tid;
    if (t < len) {
      int tagc = tags[t * TBC + bc];
      sc += em[(size_t)t * ES + (size_t)bc * Nn + tagc];
      if (t >= 1) {
        int tagp = tags[(t - 1) * TBC + bc];
        sc += trans_lds[tagp * LDP + tagc];
      }
    }
  }
  sc = wred_sum(sc);
  if (lane == 0) scw[w] = sc;
  if (tid == 0) {
    int tag0 = tags[bc];
    int tagl = tags[(len - 1) * TBC + bc];
    sc_ht = head[c * Nn + tag0] + tail[c * Nn + tagl];
  }

  // ---- per-wave P fragment (VGPRs): fwd wave = column `lane`, bwd wave = row `lane` ----
  float P[64];
  if (w == 0) {
#pragma unroll
    for (int k = 0; k < 64; ++k) P[k] = __expf(trans_lds[k * LDP + lane]);   // stride-65: conflict-free
  } else {
#pragma unroll
    for (int k = 0; k < 64; ++k) P[k] = __expf(trans_lds[lane * LDP + k]);   // stride-65: conflict-free
  }

  const float* emB = em + (size_t)bc * Nn + lane;   // &em[0, b, c, lane]
  float state = 0.f;

  if (w == 0) {
    // ======== forward: steps t = 1..m ========
    float alpha = head[c * Nn + lane] + emB[0];
    float e0 = emB[(size_t)1 * ES], e1 = emB[(size_t)2 * ES],
          e2 = emB[(size_t)3 * ES], e3 = emB[(size_t)4 * ES];
    int t = 1;
    for (; t + 3 <= m; t += 4) {                    // prefetch t+4..t+7 (<= m+4 < len, in-bounds)
      FSTEP(alpha, e0); e0 = emB[(size_t)(t + 4) * ES];
      FSTEP(alpha, e1); e1 = emB[(size_t)(t + 5) * ES];
      FSTEP(alpha, e2); e2 = emB[(size_t)(t + 6) * ES];
      FSTEP(alpha, e3); e3 = emB[(size_t)(t + 7) * ES];
    }
    if (t <= m) { FSTEP(alpha, e0); ++t; }
    if (t <= m) { FSTEP(alpha, e1); ++t; }
    if (t <= m) { FSTEP(alpha, e2); ++t; }
    state = alpha;                                  // alpha_m
  } else {
    // ======== backward: b_{len-1}=tail; steps t = len-2 down to m (k-th uses em[len-1-k]) ========
    float bv = tail[c * Nn + lane];
    const int nb = len - 1 - m;
    float e0 = emB[(size_t)(len - 1) * ES], e1 = emB[(size_t)(len - 2) * ES],
          e2 = emB[(size_t)(len - 3) * ES], e3 = emB[(size_t)(len - 4) * ES];
    int k = 0;
    for (; k + 4 <= nb; k += 4) {                   // prefetch len-5-k..len-8-k (>= m-3 >= 0)
      BSTEP(bv, e0); e0 = emB[(size_t)(len - 5 - k) * ES];
      BSTEP(bv, e1); e1 = emB[(size_t)(len - 6 - k) * ES];
      BSTEP(bv, e2); e2 = emB[(size_t)(len - 7 - k) * ES];
      BSTEP(bv, e3); e3 = emB[(size_t)(len - 8 - k) * ES];
    }
    if (k < nb) { BSTEP(bv, e0); ++k; }
    if (k < nb) { BSTEP(bv, e1); ++k; }
    if (k < nb) { BSTEP(bv, e2); ++k; }
    blds[lane] = bv;                                // beta_m
  }

  __syncthreads();                                  // both waves hit exactly once

  if (w == 0) {
    float v = state + blds[lane];                   // alpha_m + beta_m
    float mm = wred_max(v);
    float ssum = wred_sum(__expf(v - mm));
    if (lane == 0) {
      float logZ = mm + __logf(ssum);
      out[bc] = scw[0] + scw[1] + sc_ht - logZ;
    }
  }
}

extern "C" void kernel_launch(void* const* d_in, const int* in_sizes, int n_in,
                              void* d_out, int out_size, void* d_ws, size_t ws_size,
                              hipStream_t stream) {
  const float* em      = (const float*)d_in[0];
  const int*   tags    = (const int*)d_in[1];
  const int*   lengths = (const int*)d_in[2];
  const float* trans   = (const float*)d_in[3];
  const float* head    = (const float*)d_in[4];
  const float* tail    = (const float*)d_in[5];
  float* out = (float*)d_out;
  crf_fwd<<<dim3(Bn * Cn), dim3(128), 0, stream>>>(em, tags, lengths, trans, head, tail, out);
}

// Round 5
// 244.784 us; speedup vs baseline: 1.9371x; 1.0024x over previous
//
#include <hip/hip_runtime.h>
#include <cstdint>
#include <cstddef>

#define Tn 1024
#define Bn 64
#define Cn 8
#define Nn 64
#define LDP 65             /* padded row stride for trans_lds */
#define TBC 512            /* tags stride per t */
#define ES 32768           /* emissions stride per t (B*C*N) */
#define GS ((size_t)4 * ES)  /* group stride: 4 t-slices */

// ---- wave64 reductions via DPP ----
__device__ __forceinline__ float wred_max(float x) {
  int v;
#define STEP(ctrl) \
  v = __builtin_amdgcn_update_dpp((int)0xff800000, __float_as_int(x), ctrl, 0xf, 0xf, false); \
  x = fmaxf(x, __int_as_float(v));
  STEP(0x111) STEP(0x112) STEP(0x114) STEP(0x118) STEP(0x142) STEP(0x143)
#undef STEP
  return __int_as_float(__builtin_amdgcn_readlane(__float_as_int(x), 63));
}

__device__ __forceinline__ float wred_sum(float x) {
  int v;
#define STEP(ctrl) \
  v = __builtin_amdgcn_update_dpp(0, __float_as_int(x), ctrl, 0xf, 0xf, false); \
  x = x + __int_as_float(v);
  STEP(0x111) STEP(0x112) STEP(0x114) STEP(0x118) STEP(0x142) STEP(0x143)
#undef STEP
  return __int_as_float(__builtin_amdgcn_readlane(__float_as_int(x), 63));
}

__device__ __forceinline__ float lane0(float x) {
  return __int_as_float(__builtin_amdgcn_readlane(__float_as_int(x), 0));
}

// ---- in-register 64x64 matvec via readlane broadcast (P never address-taken) ----
#define RL(k) __int_as_float(__builtin_amdgcn_readlane(Ei_, (k)))
#define MV8(base) \
  a0_ = fmaf(RL(base + 0), P[base + 0], a0_); \
  a1_ = fmaf(RL(base + 1), P[base + 1], a1_); \
  a2_ = fmaf(RL(base + 2), P[base + 2], a2_); \
  a3_ = fmaf(RL(base + 3), P[base + 3], a3_); \
  a4_ = fmaf(RL(base + 4), P[base + 4], a4_); \
  a5_ = fmaf(RL(base + 5), P[base + 5], a5_); \
  a6_ = fmaf(RL(base + 6), P[base + 6], a6_); \
  a7_ = fmaf(RL(base + 7), P[base + 7], a7_);
#define MV64_BODY() \
  float a0_ = 0.f, a1_ = 0.f, a2_ = 0.f, a3_ = 0.f, a4_ = 0.f, a5_ = 0.f, a6_ = 0.f, a7_ = 0.f; \
  MV8(0) MV8(8) MV8(16) MV8(24) MV8(32) MV8(40) MV8(48) MV8(56) \
  float s_ = ((a0_ + a1_) + (a2_ + a3_)) + ((a4_ + a5_) + (a6_ + a7_));

#define FSTEP(alpha, emv) do {                      \
    float M_ = lane0(alpha);                        \
    int Ei_ = __float_as_int(__expf((alpha) - M_)); \
    MV64_BODY();                                    \
    (alpha) = M_ + __logf(s_) + (emv);              \
  } while (0)

#define BSTEP(bv, emv) do {                         \
    float v_ = (bv) + (emv);                        \
    float M_ = lane0(v_);                           \
    int Ei_ = __float_as_int(__expf(v_ - M_));      \
    MV64_BODY();                                    \
    (bv) = M_ + __logf(s_);                         \
  } while (0)

__global__ __launch_bounds__(128)
void crf_fwd(const float* __restrict__ em, const int* __restrict__ tags,
             const int* __restrict__ lengths, const float* __restrict__ trans,
             const float* __restrict__ head, const float* __restrict__ tail,
             float* __restrict__ out) {
  __shared__ float trans_lds[Nn * LDP];             // 16.6 KB
  __shared__ __align__(16) float ring[2][4 * 4 * Nn]; // per-wave 4-group em ring (2x4KB)
  __shared__ float blds[Nn];
  __shared__ float scw[2];
  __shared__ float sc_ht;

  const int bid = blockIdx.x;                       // 512 = B*C chains
  const int b = bid >> 3, c = bid & 7;
  const int tid = threadIdx.x;
  const int w = __builtin_amdgcn_readfirstlane(tid >> 6);  // 0 = fwd, 1 = bwd
  const int lane = tid & 63;
  const int bc = b * Cn + c;
  const int len = lengths[b];                       // [512, 1024]
  const int m = len >> 1;

  // ---- stage transitions[c] into LDS, stride 65 ----
  const float* tc = trans + c * Nn * Nn;
  for (int k = tid; k < Nn * Nn; k += 128) trans_lds[(k >> 6) * LDP + (k & 63)] = tc[k];
  __syncthreads();

  // ---- log_scores phase ----
  float sc = 0.f;
#pragma unroll
  for (int it = 0; it < 8; ++it) {
    int t = it * 128 + tid;
    if (t < len) {
      int tagc = tags[t * TBC + bc];
      sc += em[(size_t)t * ES + (size_t)bc * Nn + tagc];
      if (t >= 1) {
        int tagp = tags[(t - 1) * TBC + bc];
        sc += trans_lds[tagp * LDP + tagc];
      }
    }
  }
  sc = wred_sum(sc);
  if (lane == 0) scw[w] = sc;
  if (tid == 0) {
    int tag0 = tags[bc];
    int tagl = tags[(len - 1) * TBC + bc];
    sc_ht = head[c * Nn + tag0] + tail[c * Nn + tagl];
  }

  // ---- per-wave P fragment: fwd = column `lane`, bwd = row `lane` ----
  float P[64];
  if (w == 0) {
#pragma unroll
    for (int k = 0; k < 64; ++k) P[k] = __expf(trans_lds[k * LDP + lane]);
  } else {
#pragma unroll
    for (int k = 0; k < 64; ++k) P[k] = __expf(trans_lds[lane * LDP + k]);
  }

  float* myring = ring[w];
  float state = 0.f;

  if (w == 0) {
    // ======== forward: steps i=0..m-1 consume em slice t=1+i ========
    float alpha = head[c * Nn + lane] + em[(size_t)bc * Nn + lane];
    // lane L of group g loads slice 1+4g+(L>>4), cols (L&15)*4..+3
    const float* g4 = em + (size_t)(1 + (lane >> 4)) * ES + (size_t)bc * Nn + ((lane & 15) << 2);
    const int ns = m, G = ns >> 2, r = ns & 3;      // G >= 64 always (m >= 256)

    float4 v0 = *(const float4*)(g4);               // group 0
    float4 v1 = *(const float4*)(g4 + GS);          // group 1
    float4 Ast = *(const float4*)(g4 + 2 * GS);     // group 2 (staged)
    *(float4*)&myring[0 * 256 + lane * 4] = v0;
    *(float4*)&myring[1 * 256 + lane * 4] = v1;
    float c0 = myring[0 * 256 +   0 + lane], c1 = myring[0 * 256 +  64 + lane],
          c2 = myring[0 * 256 + 128 + lane], c3 = myring[0 * 256 + 192 + lane];

    for (int g = 0; g < G; ++g) {
      *(float4*)&myring[((g + 2) & 3) * 256 + lane * 4] = Ast;   // commit group g+2
      Ast = *(const float4*)(g4 + (size_t)(g + 3) * GS);         // fetch group g+3 (slice<=4G+12<=m+12, in-bounds)
      const int s1 = ((g + 1) & 3) * 256;
      float n0 = myring[s1 + lane],       n1 = myring[s1 + 64 + lane],
            n2 = myring[s1 + 128 + lane], n3 = myring[s1 + 192 + lane];
      FSTEP(alpha, c0); FSTEP(alpha, c1); FSTEP(alpha, c2); FSTEP(alpha, c3);
      c0 = n0; c1 = n1; c2 = n2; c3 = n3;
    }
    if (r > 0) { FSTEP(alpha, c0); }
    if (r > 1) { FSTEP(alpha, c1); }
    if (r > 2) { FSTEP(alpha, c2); }
    state = alpha;                                  // alpha_m
  } else {
    // ======== backward: steps k=0..nb-1 consume em slice len-1-k ========
    float bv = tail[c * Nn + lane];
    const int ns = len - 1 - m, G = ns >> 2, r = ns & 3;  // ns >= 255
    // lane L of group g loads slice len-1-4g-(L>>4)
    const float* g4 = em + (size_t)(len - 1 - (lane >> 4)) * ES + (size_t)bc * Nn + ((lane & 15) << 2);

    float4 v0 = *(const float4*)(g4);               // group 0
    float4 v1 = *(const float4*)(g4 - GS);          // group 1
    float4 Ast = *(const float4*)(g4 - 2 * GS);     // group 2
    *(float4*)&myring[0 * 256 + lane * 4] = v0;
    *(float4*)&myring[1 * 256 + lane * 4] = v1;
    float c0 = myring[0 * 256 +   0 + lane], c1 = myring[0 * 256 +  64 + lane],
          c2 = myring[0 * 256 + 128 + lane], c3 = myring[0 * 256 + 192 + lane];

    for (int g = 0; g < G; ++g) {
      *(float4*)&myring[((g + 2) & 3) * 256 + lane * 4] = Ast;
      Ast = *(const float4*)(g4 - (size_t)(g + 3) * GS);         // slice >= m-11 >= 0, in-bounds
      const int s1 = ((g + 1) & 3) * 256;
      float n0 = myring[s1 + lane],       n1 = myring[s1 + 64 + lane],
            n2 = myring[s1 + 128 + lane], n3 = myring[s1 + 192 + lane];
      BSTEP(bv, c0); BSTEP(bv, c1); BSTEP(bv, c2); BSTEP(bv, c3);
      c0 = n0; c1 = n1; c2 = n2; c3 = n3;
    }
    if (r > 0) { BSTEP(bv, c0); }
    if (r > 1) { BSTEP(bv, c1); }
    if (r > 2) { BSTEP(bv, c2); }
    blds[lane] = bv;                                // beta_m
  }

  __syncthreads();                                  // both waves hit exactly once

  if (w == 0) {
    float v = state + blds[lane];                   // alpha_m + beta_m
    float mm = wred_max(v);
    float ssum = wred_sum(__expf(v - mm));
    if (lane == 0) {
      float logZ = mm + __logf(ssum);
      out[bc] = scw[0] + scw[1] + sc_ht - logZ;
    }
  }
}

extern "C" void kernel_launch(void* const* d_in, const int* in_sizes, int n_in,
                              void* d_out, int out_size, void* d_ws, size_t ws_size,
                              hipStream_t stream) {
  const float* em      = (const float*)d_in[0];
  const int*   tags    = (const int*)d_in[1];
  const int*   lengths = (const int*)d_in[2];
  const float* trans   = (const float*)d_in[3];
  const float* head    = (const float*)d_in[4];
  const float* tail    = (const float*)d_in[5];
  float* out = (float*)d_out;
  crf_fwd<<<dim3(Bn * Cn), dim3(128), 0, stream>>>(em, tags, lengths, trans, head, tail, out);
}

// Round 7
// 217.410 us; speedup vs baseline: 2.1809x; 1.1259x over previous
//
#include <hip/hip_runtime.h>
#include <cstdint>
#include <cstddef>

#define Tn 1024
#define Bn 64
#define Cn 8
#define Nn 64
#define LDP 65             /* padded row stride for trans_lds */
#define TBC 512            /* tags stride per t */
#define ES 32768           /* emissions stride per t (B*C*N) */
#define GS ((size_t)4 * ES)  /* group stride: 4 t-slices */
#define LN2F 0.69314718056f

// ---- wave64 reductions via DPP ----
__device__ __forceinline__ float wred_max(float x) {
  int v;
#define STEP(ctrl) \
  v = __builtin_amdgcn_update_dpp((int)0xff800000, __float_as_int(x), ctrl, 0xf, 0xf, false); \
  x = fmaxf(x, __int_as_float(v));
  STEP(0x111) STEP(0x112) STEP(0x114) STEP(0x118) STEP(0x142) STEP(0x143)
#undef STEP
  return __int_as_float(__builtin_amdgcn_readlane(__float_as_int(x), 63));
}

__device__ __forceinline__ float wred_sum(float x) {
  int v;
#define STEP(ctrl) \
  v = __builtin_amdgcn_update_dpp(0, __float_as_int(x), ctrl, 0xf, 0xf, false); \
  x = x + __int_as_float(v);
  STEP(0x111) STEP(0x112) STEP(0x114) STEP(0x118) STEP(0x142) STEP(0x143)
#undef STEP
  return __int_as_float(__builtin_amdgcn_readlane(__float_as_int(x), 63));
}

__device__ __forceinline__ float lane0(float x) {
  return __int_as_float(__builtin_amdgcn_readlane(__float_as_int(x), 0));
}

// ---- in-register 64x64 matvec via readlane broadcast (P never address-taken) ----
#define RL(k) __int_as_float(__builtin_amdgcn_readlane(Ei_, (k)))
#define MV8(base) \
  a0_ = fmaf(RL(base + 0), P[base + 0], a0_); \
  a1_ = fmaf(RL(base + 1), P[base + 1], a1_); \
  a2_ = fmaf(RL(base + 2), P[base + 2], a2_); \
  a3_ = fmaf(RL(base + 3), P[base + 3], a3_); \
  a4_ = fmaf(RL(base + 4), P[base + 4], a4_); \
  a5_ = fmaf(RL(base + 5), P[base + 5], a5_); \
  a6_ = fmaf(RL(base + 6), P[base + 6], a6_); \
  a7_ = fmaf(RL(base + 7), P[base + 7], a7_);
#define MV64_BODY() \
  float a0_ = 0.f, a1_ = 0.f, a2_ = 0.f, a3_ = 0.f, a4_ = 0.f, a5_ = 0.f, a6_ = 0.f, a7_ = 0.f; \
  MV8(0) MV8(8) MV8(16) MV8(24) MV8(32) MV8(40) MV8(48) MV8(56) \
  float s_ = ((a0_ + a1_) + (a2_ + a3_)) + ((a4_ + a5_) + (a6_ + a7_));

// Linear-space forward step: u'_j = w_j * sum_i P_ij u_i   (w = e^{em_t}, P = e^{trans})
#define FSTEP_LIN(u, wv) do {                       \
    int Ei_ = __float_as_int(u);                    \
    MV64_BODY();                                    \
    (u) = s_ * (wv);                                \
  } while (0)

// Linear-space backward step: v_i = sum_j P_ij (w_j v'_j)  (w = e^{em_{t+1}})
#define BSTEP_LIN(v, wv) do {                       \
    int Ei_ = __float_as_int((v) * (wv));           \
    MV64_BODY();                                    \
    (v) = s_;                                       \
  } while (0)

// Exact 2^-k rescale; k accumulated as integer (no rounding error).
#define RESCALE(u, Lk) do {                         \
    float mx_ = wred_max(u);                        \
    int ke_ = (__float_as_int(mx_) >> 23) & 255;    \
    (Lk) += ke_ - 127;                              \
    (u) *= __int_as_float((254 - ke_) << 23);       \
  } while (0)

__global__ __launch_bounds__(128)
void crf_fwd(const float* __restrict__ em, const int* __restrict__ tags,
             const int* __restrict__ lengths, const float* __restrict__ trans,
             const float* __restrict__ head, const float* __restrict__ tail,
             float* __restrict__ out) {
  __shared__ float trans_lds[Nn * LDP];               // 16.6 KB
  __shared__ __align__(16) float ring[2][4 * 4 * Nn]; // per-wave 4-group em ring
  __shared__ float blds[Nn];
  __shared__ float scw[2];
  __shared__ float sc_ht;
  __shared__ float lbshift;                           // bwd wave's total log-shift

  const int bid = blockIdx.x;                         // 512 = B*C chains
  const int b = bid >> 3, c = bid & 7;
  const int tid = threadIdx.x;
  const int w = __builtin_amdgcn_readfirstlane(tid >> 6);  // 0 = fwd, 1 = bwd
  const int lane = tid & 63;
  const int bc = b * Cn + c;
  const int len = lengths[b];                         // [512, 1024]
  const int m = len >> 1;

  // ---- stage transitions[c] into LDS, stride 65 ----
  const float* tc = trans + c * Nn * Nn;
  for (int k = tid; k < Nn * Nn; k += 128) trans_lds[(k >> 6) * LDP + (k & 63)] = tc[k];
  __syncthreads();

  // ---- log_scores phase ----
  float sc = 0.f;
#pragma unroll
  for (int it = 0; it < 8; ++it) {
    int t = it * 128 + tid;
    if (t < len) {
      int tagc = tags[t * TBC + bc];
      sc += em[(size_t)t * ES + (size_t)bc * Nn + tagc];
      if (t >= 1) {
        int tagp = tags[(t - 1) * TBC + bc];
        sc += trans_lds[tagp * LDP + tagc];
      }
    }
  }
  sc = wred_sum(sc);
  if (lane == 0) scw[w] = sc;
  if (tid == 0) {
    int tag0 = tags[bc];
    int tagl = tags[(len - 1) * TBC + bc];
    sc_ht = head[c * Nn + tag0] + tail[c * Nn + tagl];
  }

  // ---- per-wave P fragment: fwd = column `lane`, bwd = row `lane` ----
  float P[64];
  if (w == 0) {
#pragma unroll
    for (int k = 0; k < 64; ++k) P[k] = __expf(trans_lds[k * LDP + lane]);
  } else {
#pragma unroll
    for (int k = 0; k < 64; ++k) P[k] = __expf(trans_lds[lane * LDP + k]);
  }

  float* myring = ring[w];
  float state = 0.f;
  float shift0 = 0.f;     // A0 / B0
  int   Lk = 0;           // accumulated power-of-2 shift (exact)

  if (w == 0) {
    // ======== forward: steps i=0..m-1 consume em slice t=1+i ========
    float al0 = head[c * Nn + lane] + em[(size_t)bc * Nn + lane];
    shift0 = lane0(al0);
    float u = __expf(al0 - shift0);                 // |al0 - A0| small, safe
    const float* g4 = em + (size_t)(1 + (lane >> 4)) * ES + (size_t)bc * Nn + ((lane & 15) << 2);
    const int ns = m, G = ns >> 2, r = ns & 3;      // G >= 64

    float4 v0 = *(const float4*)(g4);               // group 0
    float4 v1 = *(const float4*)(g4 + GS);          // group 1
    float4 Ast = *(const float4*)(g4 + 2 * GS);     // group 2 (staged)
    *(float4*)&myring[0 * 256 + lane * 4] = v0;
    *(float4*)&myring[1 * 256 + lane * 4] = v1;
    float c0 = __expf(myring[0 * 256 +   0 + lane]), c1 = __expf(myring[0 * 256 +  64 + lane]),
          c2 = __expf(myring[0 * 256 + 128 + lane]), c3 = __expf(myring[0 * 256 + 192 + lane]);

    for (int g = 0; g < G; ++g) {
      *(float4*)&myring[((g + 2) & 3) * 256 + lane * 4] = Ast;   // commit group g+2
      Ast = *(const float4*)(g4 + (size_t)(g + 3) * GS);         // fetch group g+3 (slice <= m+12 < 1024)
      const int s1 = ((g + 1) & 3) * 256;
      float n0 = myring[s1 + lane],       n1 = myring[s1 + 64 + lane],
            n2 = myring[s1 + 128 + lane], n3 = myring[s1 + 192 + lane];
      FSTEP_LIN(u, c0); FSTEP_LIN(u, c1); FSTEP_LIN(u, c2); FSTEP_LIN(u, c3);
      RESCALE(u, Lk);
      c0 = __expf(n0); c1 = __expf(n1); c2 = __expf(n2); c3 = __expf(n3);
    }
    if (r > 0) { FSTEP_LIN(u, c0); }
    if (r > 1) { FSTEP_LIN(u, c1); }
    if (r > 2) { FSTEP_LIN(u, c2); }
    RESCALE(u, Lk);                                 // normalize meet-point vector (exact)
    state = u;                                      // u_m = e^{alpha_m - A0 - Lk*ln2}
  } else {
    // ======== backward: steps k=0..nb-1 consume em slice len-1-k ========
    float tl = tail[c * Nn + lane];
    shift0 = lane0(tl);
    float v = __expf(tl - shift0);
    const int ns = len - 1 - m, G = ns >> 2, r = ns & 3;  // ns >= 255
    const float* g4 = em + (size_t)(len - 1 - (lane >> 4)) * ES + (size_t)bc * Nn + ((lane & 15) << 2);

    float4 v0 = *(const float4*)(g4);               // group 0
    float4 v1 = *(const float4*)(g4 - GS);          // group 1
    float4 Ast = *(const float4*)(g4 - 2 * GS);     // group 2
    *(float4*)&myring[0 * 256 + lane * 4] = v0;
    *(float4*)&myring[1 * 256 + lane * 4] = v1;
    float c0 = __expf(myring[0 * 256 +   0 + lane]), c1 = __expf(myring[0 * 256 +  64 + lane]),
          c2 = __expf(myring[0 * 256 + 128 + lane]), c3 = __expf(myring[0 * 256 + 192 + lane]);

    for (int g = 0; g < G; ++g) {
      *(float4*)&myring[((g + 2) & 3) * 256 + lane * 4] = Ast;
      Ast = *(const float4*)(g4 - (size_t)(g + 3) * GS);         // slice >= m-11 >= 0
      const int s1 = ((g + 1) & 3) * 256;
      float n0 = myring[s1 + lane],       n1 = myring[s1 + 64 + lane],
            n2 = myring[s1 + 128 + lane], n3 = myring[s1 + 192 + lane];
      BSTEP_LIN(v, c0); BSTEP_LIN(v, c1); BSTEP_LIN(v, c2); BSTEP_LIN(v, c3);
      RESCALE(v, Lk);
      c0 = __expf(n0); c1 = __expf(n1); c2 = __expf(n2); c3 = __expf(n3);
    }
    if (r > 0) { BSTEP_LIN(v, c0); }
    if (r > 1) { BSTEP_LIN(v, c1); }
    if (r > 2) { BSTEP_LIN(v, c2); }
    RESCALE(v, Lk);                                 // normalize meet-point vector (exact)
    blds[lane] = v;                                 // v_m = e^{beta_m - B0 - Lk*ln2}
    if (lane == 0) lbshift = shift0 + (float)Lk * LN2F;
  }

  __syncthreads();                                  // both waves hit exactly once

  if (w == 0) {
    float p = state * blds[lane];                   // e^{alpha_m + beta_m - shifts}, max ~4
    float ssum = wred_sum(p);                       // positive terms, no cancellation
    if (lane == 0) {
      float logZ = __logf(ssum) + shift0 + (float)Lk * LN2F + lbshift;
      out[bc] = scw[0] + scw[1] + sc_ht - logZ;
    }
  }
}

extern "C" void kernel_launch(void* const* d_in, const int* in_sizes, int n_in,
                              void* d_out, int out_size, void* d_ws, size_t ws_size,
                              hipStream_t stream) {
  const float* em      = (const float*)d_in[0];
  const int*   tags    = (const int*)d_in[1];
  const int*   lengths = (const int*)d_in[2];
  const float* trans   = (const float*)d_in[3];
  const float* head    = (const float*)d_in[4];
  const float* tail    = (const float*)d_in[5];
  float* out = (float*)d_out;
  crf_fwd<<<dim3(Bn * Cn), dim3(128), 0, stream>>>(em, tags, lengths, trans, head, tail, out);
}

// Round 8
// 127.336 us; speedup vs baseline: 3.7237x; 1.7074x over previous
//
#include <hip/hip_runtime.h>
#include <cstdint>
#include <cstddef>

#define Tn 1024
#define Bn 64
#define Cn 8
#define Nn 64
#define LDP 65             /* padded row stride for trans_lds */
#define TBC 512            /* tags stride per t */
#define ES 32768           /* emissions stride per t (B*C*N) */
#define GS ((size_t)4 * ES)  /* group stride: 4 t-slices */
#define LN2F 0.69314718056f

typedef float f32x2 __attribute__((ext_vector_type(2)));
typedef float f32x4 __attribute__((ext_vector_type(4)));

// ---- wave64 reductions via DPP ----
__device__ __forceinline__ float wred_max(float x) {
  int v;
#define STEP(ctrl) \
  v = __builtin_amdgcn_update_dpp((int)0xff800000, __float_as_int(x), ctrl, 0xf, 0xf, false); \
  x = fmaxf(x, __int_as_float(v));
  STEP(0x111) STEP(0x112) STEP(0x114) STEP(0x118) STEP(0x142) STEP(0x143)
#undef STEP
  return __int_as_float(__builtin_amdgcn_readlane(__float_as_int(x), 63));
}

__device__ __forceinline__ float wred_sum(float x) {
  int v;
#define STEP(ctrl) \
  v = __builtin_amdgcn_update_dpp(0, __float_as_int(x), ctrl, 0xf, 0xf, false); \
  x = x + __int_as_float(v);
  STEP(0x111) STEP(0x112) STEP(0x114) STEP(0x118) STEP(0x142) STEP(0x143)
#undef STEP
  return __int_as_float(__builtin_amdgcn_readlane(__float_as_int(x), 63));
}

__device__ __forceinline__ float lane0(float x) {
  return __int_as_float(__builtin_amdgcn_readlane(__float_as_int(x), 0));
}

// ---- LDS-uniform-broadcast 64x64 matvec ----
// Lane j wrote u_j to ew[j]; all lanes then read ew[] at UNIFORM addresses
// (ds_read_b128 broadcast, conflict-free) and accumulate with packed f32x2
// FMAs against the register-resident P2 fragment (never address-taken).
#define MQ(q, A, B) { f32x4 t_ = eq4_[q]; \
    A += __builtin_shufflevector(t_, t_, 0, 1) * P2[2*(q)]; \
    B += __builtin_shufflevector(t_, t_, 2, 3) * P2[2*(q)+1]; }
#define MVBODY() \
  f32x2 A0_ = {0.f, 0.f}, A1_ = A0_, A2_ = A0_, A3_ = A0_; \
  { const f32x4* eq4_ = (const f32x4*)ew; \
    MQ(0,A0_,A1_)  MQ(1,A2_,A3_)  MQ(2,A0_,A1_)  MQ(3,A2_,A3_) \
    MQ(4,A0_,A1_)  MQ(5,A2_,A3_)  MQ(6,A0_,A1_)  MQ(7,A2_,A3_) \
    MQ(8,A0_,A1_)  MQ(9,A2_,A3_)  MQ(10,A0_,A1_) MQ(11,A2_,A3_) \
    MQ(12,A0_,A1_) MQ(13,A2_,A3_) MQ(14,A0_,A1_) MQ(15,A2_,A3_) } \
  f32x2 S01_ = A0_ + A1_, S23_ = A2_ + A3_; \
  f32x2 S_ = S01_ + S23_; \
  float s_ = S_.x + S_.y;

// Linear-space forward step: u'_j = w_j * sum_i P_ij u_i
#define FSTEP_LIN(u, wv) do {                       \
    ew[lane] = (u);                                 \
    MVBODY();                                       \
    (u) = s_ * (wv);                                \
  } while (0)

// Linear-space backward step: v_i = sum_j P_ij (w_j v'_j)
#define BSTEP_LIN(v, wv) do {                       \
    ew[lane] = (v) * (wv);                          \
    MVBODY();                                       \
    (v) = s_;                                       \
  } while (0)

// Cheap on-chain rescale: exponent of lane0's value (spread across lanes is
// bounded by ~2^22, growth per 4 steps <= 2^41 -> no overflow; exact 2^-k).
#define RESCALE0(u, Lk) do {                        \
    int ke_ = (__builtin_amdgcn_readlane(__float_as_int(u), 0) >> 23) & 255; \
    (Lk) += ke_ - 127;                              \
    (u) *= __int_as_float((254 - ke_) << 23);       \
  } while (0)

// Exact max-based rescale (epilogue only).
#define RESCALE(u, Lk) do {                         \
    float mx_ = wred_max(u);                        \
    int ke_ = (__float_as_int(mx_) >> 23) & 255;    \
    (Lk) += ke_ - 127;                              \
    (u) *= __int_as_float((254 - ke_) << 23);       \
  } while (0)

__global__ __launch_bounds__(128)
void crf_fwd(const float* __restrict__ em, const int* __restrict__ tags,
             const int* __restrict__ lengths, const float* __restrict__ trans,
             const float* __restrict__ head, const float* __restrict__ tail,
             float* __restrict__ out) {
  __shared__ float trans_lds[Nn * LDP];               // 16.6 KB
  __shared__ __align__(16) float ring[2][4 * 4 * Nn]; // per-wave 4-group em ring
  __shared__ __align__(16) float ebuf[2][Nn];         // per-wave broadcast buffer
  __shared__ float blds[Nn];
  __shared__ float scw[2];
  __shared__ float sc_ht;
  __shared__ float lbshift;

  const int bid = blockIdx.x;                         // 512 = B*C chains
  const int b = bid >> 3, c = bid & 7;
  const int tid = threadIdx.x;
  const int w = __builtin_amdgcn_readfirstlane(tid >> 6);  // 0 = fwd, 1 = bwd
  const int lane = tid & 63;
  const int bc = b * Cn + c;
  const int len = lengths[b];                         // [512, 1024]
  const int m = len >> 1;

  // ---- stage transitions[c] into LDS, stride 65 ----
  const float* tc = trans + c * Nn * Nn;
  for (int k = tid; k < Nn * Nn; k += 128) trans_lds[(k >> 6) * LDP + (k & 63)] = tc[k];
  __syncthreads();

  // ---- log_scores phase ----
  float sc = 0.f;
#pragma unroll
  for (int it = 0; it < 8; ++it) {
    int t = it * 128 + tid;
    if (t < len) {
      int tagc = tags[t * TBC + bc];
      sc += em[(size_t)t * ES + (size_t)bc * Nn + tagc];
      if (t >= 1) {
        int tagp = tags[(t - 1) * TBC + bc];
        sc += trans_lds[tagp * LDP + tagc];
      }
    }
  }
  sc = wred_sum(sc);
  if (lane == 0) scw[w] = sc;
  if (tid == 0) {
    int tag0 = tags[bc];
    int tagl = tags[(len - 1) * TBC + bc];
    sc_ht = head[c * Nn + tag0] + tail[c * Nn + tagl];
  }

  // ---- per-wave P2 fragment (f32x2 pairs, VGPR-resident) ----
  // fwd: P[i] = exp(trans[i][lane]);  bwd: P[j] = exp(trans[lane][j])
  f32x2 P2[32];
  if (w == 0) {
#pragma unroll
    for (int k = 0; k < 32; ++k) {
      f32x2 p; p.x = __expf(trans_lds[(2 * k) * LDP + lane]);
      p.y = __expf(trans_lds[(2 * k + 1) * LDP + lane]);
      P2[k] = p;
    }
  } else {
#pragma unroll
    for (int k = 0; k < 32; ++k) {
      f32x2 p; p.x = __expf(trans_lds[lane * LDP + 2 * k]);
      p.y = __expf(trans_lds[lane * LDP + 2 * k + 1]);
      P2[k] = p;
    }
  }

  float* myring = ring[w];
  float* ew = ebuf[w];
  float state = 0.f;
  float shift0 = 0.f;
  int   Lk = 0;

  if (w == 0) {
    // ======== forward: steps i=0..m-1 consume em slice t=1+i ========
    float al0 = head[c * Nn + lane] + em[(size_t)bc * Nn + lane];
    shift0 = lane0(al0);
    float u = __expf(al0 - shift0);
    const float* g4 = em + (size_t)(1 + (lane >> 4)) * ES + (size_t)bc * Nn + ((lane & 15) << 2);
    const int ns = m, G = ns >> 2, r = ns & 3;

    float4 v0 = *(const float4*)(g4);
    float4 v1 = *(const float4*)(g4 + GS);
    float4 Ast = *(const float4*)(g4 + 2 * GS);
    *(float4*)&myring[0 * 256 + lane * 4] = v0;
    *(float4*)&myring[1 * 256 + lane * 4] = v1;
    float c0 = __expf(myring[0 * 256 +   0 + lane]), c1 = __expf(myring[0 * 256 +  64 + lane]),
          c2 = __expf(myring[0 * 256 + 128 + lane]), c3 = __expf(myring[0 * 256 + 192 + lane]);

    for (int g = 0; g < G; ++g) {
      *(float4*)&myring[((g + 2) & 3) * 256 + lane * 4] = Ast;   // commit group g+2
      Ast = *(const float4*)(g4 + (size_t)(g + 3) * GS);         // fetch group g+3 (slice <= m+12 < 1024)
      const int s1 = ((g + 1) & 3) * 256;
      float n0 = myring[s1 + lane],       n1 = myring[s1 + 64 + lane],
            n2 = myring[s1 + 128 + lane], n3 = myring[s1 + 192 + lane];
      FSTEP_LIN(u, c0); FSTEP_LIN(u, c1); FSTEP_LIN(u, c2); FSTEP_LIN(u, c3);
      RESCALE0(u, Lk);
      c0 = __expf(n0); c1 = __expf(n1); c2 = __expf(n2); c3 = __expf(n3);
    }
    if (r > 0) { FSTEP_LIN(u, c0); }
    if (r > 1) { FSTEP_LIN(u, c1); }
    if (r > 2) { FSTEP_LIN(u, c2); }
    RESCALE(u, Lk);                                 // exact normalize at meet point
    state = u;                                      // u_m = e^{alpha_m - A0 - Lk*ln2}
  } else {
    // ======== backward: steps k=0..nb-1 consume em slice len-1-k ========
    float tl = tail[c * Nn + lane];
    shift0 = lane0(tl);
    float v = __expf(tl - shift0);
    const int ns = len - 1 - m, G = ns >> 2, r = ns & 3;
    const float* g4 = em + (size_t)(len - 1 - (lane >> 4)) * ES + (size_t)bc * Nn + ((lane & 15) << 2);

    float4 v0 = *(const float4*)(g4);
    float4 v1 = *(const float4*)(g4 - GS);
    float4 Ast = *(const float4*)(g4 - 2 * GS);
    *(float4*)&myring[0 * 256 + lane * 4] = v0;
    *(float4*)&myring[1 * 256 + lane * 4] = v1;
    float c0 = __expf(myring[0 * 256 +   0 + lane]), c1 = __expf(myring[0 * 256 +  64 + lane]),
          c2 = __expf(myring[0 * 256 + 128 + lane]), c3 = __expf(myring[0 * 256 + 192 + lane]);

    for (int g = 0; g < G; ++g) {
      *(float4*)&myring[((g + 2) & 3) * 256 + lane * 4] = Ast;
      Ast = *(const float4*)(g4 - (size_t)(g + 3) * GS);         // slice >= m-11 >= 0
      const int s1 = ((g + 1) & 3) * 256;
      float n0 = myring[s1 + lane],       n1 = myring[s1 + 64 + lane],
            n2 = myring[s1 + 128 + lane], n3 = myring[s1 + 192 + lane];
      BSTEP_LIN(v, c0); BSTEP_LIN(v, c1); BSTEP_LIN(v, c2); BSTEP_LIN(v, c3);
      RESCALE0(v, Lk);
      c0 = __expf(n0); c1 = __expf(n1); c2 = __expf(n2); c3 = __expf(n3);
    }
    if (r > 0) { BSTEP_LIN(v, c0); }
    if (r > 1) { BSTEP_LIN(v, c1); }
    if (r > 2) { BSTEP_LIN(v, c2); }
    RESCALE(v, Lk);                                 // exact normalize at meet point
    blds[lane] = v;                                 // v_m = e^{beta_m - B0 - Lk*ln2}
    if (lane == 0) lbshift = shift0 + (float)Lk * LN2F;
  }

  __syncthreads();                                  // both waves hit exactly once

  if (w == 0) {
    float p = state * blds[lane];                   // max ~4, positive terms
    float ssum = wred_sum(p);
    if (lane == 0) {
      float logZ = __logf(ssum) + shift0 + (float)Lk * LN2F + lbshift;
      out[bc] = scw[0] + scw[1] + sc_ht - logZ;
    }
  }
}

extern "C" void kernel_launch(void* const* d_in, const int* in_sizes, int n_in,
                              void* d_out, int out_size, void* d_ws, size_t ws_size,
                              hipStream_t stream) {
  const float* em      = (const float*)d_in[0];
  const int*   tags    = (const int*)d_in[1];
  const int*   lengths = (const int*)d_in[2];
  const float* trans   = (const float*)d_in[3];
  const float* head    = (const float*)d_in[4];
  const float* tail    = (const float*)d_in[5];
  float* out = (float*)d_out;
  crf_fwd<<<dim3(Bn * Cn), dim3(128), 0, stream>>>(em, tags, lengths, trans, head, tail, out);
}